// Round 6
// baseline (1998.609 us; speedup 1.0000x reference)
//
#include <hip/hip_runtime.h>
#include <math.h>

#define T_   2048
#define DIN  512
#define H_   384
#define H4_  1536
#define BT_  16384

typedef _Float16 half_t;
typedef _Float16 f16x8 __attribute__((ext_vector_type(8)));
typedef _Float16 f16x4 __attribute__((ext_vector_type(4)));
typedef float f32x4 __attribute__((ext_vector_type(4)));

#define LO_SCALE 2048.0f
#define LO_INV   4.8828125e-4f

// LDS staging geometry: row stride 36 halves (72 B). dword-stride 18,
// gcd(18,32)=2 -> 16 consecutive rows start at 16 distinct even banks;
// all LDS ops are b64 -> provably uniform bank load (no conflicts).
#define ASTRIDE 36
#define ASEG    2304    // 64 rows * 36
#define APLANE  4608    // 128 rows * 36
#define ASL_OFF 9216    // 2 bufs * APLANE
#define BSH_OFF 18432
#define BPLANE  2304    // 64 rows * 36
#define BSL_OFF 23040
#define SMEM_H  27648   // halves (54 KB)

// lgkm-only barrier: prefetched global->VGPR loads stay in flight across it.
__device__ __forceinline__ void lds_barrier() {
    asm volatile("s_waitcnt lgkmcnt(0)\n\ts_barrier" ::: "memory");
}

__device__ __forceinline__ void split2(float v, half_t* hi, half_t* lo) {
    half_t h = (half_t)v;
    *hi = h;
    *lo = (half_t)((v - (float)h) * LO_SCALE);
}

// ---------------------------------------------------------------------------
// fp32 -> (hi, lo*2048) fp16 element-wise split
// ---------------------------------------------------------------------------
__global__ void k_split(const float* __restrict__ in, half_t* __restrict__ hi,
                        half_t* __restrict__ lo, long n) {
    long i = (long)blockIdx.x * 256 + threadIdx.x;
    if (i >= n) return;
    split2(in[i], hi + i, lo + i);
}

// enc_w [H][DIN][7] -> [H][tap*512+i] hi/lo
__global__ void k_split_encw(const float* __restrict__ in, half_t* __restrict__ hi,
                             half_t* __restrict__ lo) {
    int idx = blockIdx.x * 256 + threadIdx.x;
    if (idx >= H_ * 3584) return;
    int n = idx / 3584;
    int r = idx % 3584;
    int tap = r >> 9, i = r & 511;
    split2(in[n * 3584 + i * 7 + tap], hi + idx, lo + idx);
}

// ---------------------------------------------------------------------------
// Row-wise LayerNorm over H=384 (fp32 in/out, in-place safe), one wave per row
// ---------------------------------------------------------------------------
__global__ void k_ln(const float* __restrict__ in, float* __restrict__ out,
                     const float* __restrict__ g, const float* __restrict__ b) {
    int row = blockIdx.x;
    int lane = threadIdx.x;
    const float* ir = in + (long)row * H_;
    float v[6];
    float s = 0.f;
#pragma unroll
    for (int j = 0; j < 6; ++j) { v[j] = ir[lane + (j << 6)]; s += v[j]; }
#pragma unroll
    for (int o = 32; o > 0; o >>= 1) s += __shfl_down(s, o, 64);
    s = __shfl(s, 0, 64);
    float mean = s * (1.f / 384.f);
    float q = 0.f;
#pragma unroll
    for (int j = 0; j < 6; ++j) { float d = v[j] - mean; q += d * d; }
#pragma unroll
    for (int o = 32; o > 0; o >>= 1) q += __shfl_down(q, o, 64);
    q = __shfl(q, 0, 64);
    float rstd = rsqrtf(q * (1.f / 384.f) + 1e-5f);
    float* orow = out + (long)row * H_;
#pragma unroll
    for (int j = 0; j < 6; ++j) {
        int c = lane + (j << 6);
        orow[c] = (v[j] - mean) * rstd * g[c] + b[c];
    }
}

// ---------------------------------------------------------------------------
// Fused depthwise conv (k=7, pad=3) + LayerNorm; emits fp16 hi/lo for GEMM1
// 4 rows per block (one per wave) so the 7-tap t-overlap is L1-resident.
// ---------------------------------------------------------------------------
__global__ __launch_bounds__(256) void k_dwconv_ln(
    const float* __restrict__ h, half_t* __restrict__ oh,
    half_t* __restrict__ ol,
    const float* __restrict__ w, const float* __restrict__ wb,
    const float* __restrict__ g, const float* __restrict__ gb) {
    int row = (blockIdx.x << 2) + (threadIdx.x >> 6);
    int b = row >> 11;
    int t = row & 2047;
    int lane = threadIdx.x & 63;
    const float* hb = h + ((long)b * T_) * H_;
    float v[6];
    float s = 0.f;
#pragma unroll
    for (int j = 0; j < 6; ++j) {
        int c = lane + (j << 6);
        float acc = wb[c];
        const float* wc = w + c * 7;
#pragma unroll
        for (int k = 0; k < 7; ++k) {
            int tt = t + k - 3;
            if ((unsigned)tt < (unsigned)T_)
                acc = fmaf(hb[(long)tt * H_ + c], wc[k], acc);
        }
        v[j] = acc;
        s += acc;
    }
#pragma unroll
    for (int o = 32; o > 0; o >>= 1) s += __shfl_down(s, o, 64);
    s = __shfl(s, 0, 64);
    float mean = s * (1.f / 384.f);
    float q = 0.f;
#pragma unroll
    for (int j = 0; j < 6; ++j) { float d = v[j] - mean; q += d * d; }
#pragma unroll
    for (int o = 32; o > 0; o >>= 1) q += __shfl_down(q, o, 64);
    q = __shfl(q, 0, 64);
    float rstd = rsqrtf(q * (1.f / 384.f) + 1e-5f);
    long ro = (long)row * H_;
#pragma unroll
    for (int j = 0; j < 6; ++j) {
        int c = lane + (j << 6);
        float val = (v[j] - mean) * rstd * g[c] + gb[c];
        split2(val, oh + ro + c, ol + ro + c);
    }
}

// ---------------------------------------------------------------------------
// MFMA fp16x3 GEMM: C = A@B^T(+bias...), A [M][K] hi/lo fp16, B [N][K] hi/lo.
// BM=128, BN=64, BK=32; 4 waves, wave tile 64x32 (4x2 frags of 16x16x32).
// lo terms pre-scaled by 2048, accumulated separately, recombined at epilogue.
// MODE 0: A = x im2row (K=3584), +bias, fp32 out; grid x=m (B L2-resident/XCD)
// MODE 1: +bias, exact GELU, fp16 hi/lo out; grid x=n (A-slice L2 reuse)
// MODE 2: +bias, +res, fp32 out; grid x=n
// ---------------------------------------------------------------------------
template <int MODE>
__global__ __launch_bounds__(256) void k_mgemm(
    const half_t* __restrict__ Ah, const half_t* __restrict__ Al,
    const half_t* __restrict__ Bh, const half_t* __restrict__ Bl,
    const float* __restrict__ bias, const float* __restrict__ res,
    float* __restrict__ Cf, half_t* __restrict__ Ch, half_t* __restrict__ Cl,
    int N, int K) {
    __shared__ __align__(16) half_t smem[SMEM_H];
    const int tid = threadIdx.x;
    const int lane = tid & 63, wid = tid >> 6;
    const int wm = (wid >> 1) << 6, wn = (wid & 1) << 5;
    const int quad = lane >> 4, l16 = lane & 15;
    const int m0 = (MODE == 0 ? blockIdx.x : blockIdx.y) << 7;
    const int n0 = (MODE == 0 ? blockIdx.y : blockIdx.x) << 6;
    const int ar = tid >> 2;          // A row for seg0 (0..63), seg1 = +64
    const int ak = (tid & 3) << 3;    // k offset (halves)
    const int br = tid >> 2, bk = (tid & 3) << 3;

    long aoff0 = 0, aoff1 = 0;
    int tt0 = 0, tt1 = 0, bq = 0;
    if (MODE == 0) {
        bq = m0 >> 11;
        tt0 = (m0 & 2047) + ar - 3;
        tt1 = tt0 + 64;
    } else {
        aoff0 = (long)(m0 + ar) * K + ak;
        aoff1 = aoff0 + (long)64 * K;
    }
    const long boff = (long)(n0 + br) * K + bk;

    float4 pa0h, pa0l, pa1h, pa1l, pbh, pbl;
    auto loadregs = [&](int k0) {
        if (MODE == 0) {
            int kk = k0 + ak;
            int tap = kk >> 9, ii = kk & 511;
            int ta = tt0 + tap, tb = tt1 + tap;
            pa0h = pa0l = pa1h = pa1l = make_float4(0.f, 0.f, 0.f, 0.f);
            if ((unsigned)ta < 2048u) {
                long o = ((long)bq * 2048 + ta) * 512 + ii;
                pa0h = *(const float4*)(Ah + o);
                pa0l = *(const float4*)(Al + o);
            }
            if ((unsigned)tb < 2048u) {
                long o = ((long)bq * 2048 + tb) * 512 + ii;
                pa1h = *(const float4*)(Ah + o);
                pa1l = *(const float4*)(Al + o);
            }
        } else {
            pa0h = *(const float4*)(Ah + aoff0 + k0);
            pa0l = *(const float4*)(Al + aoff0 + k0);
            pa1h = *(const float4*)(Ah + aoff1 + k0);
            pa1l = *(const float4*)(Al + aoff1 + k0);
        }
        pbh = *(const float4*)(Bh + boff + k0);
        pbl = *(const float4*)(Bl + boff + k0);
    };
    const int aw = ar * ASTRIDE + ak;
    const int bw = br * ASTRIDE + bk;
    auto st64 = [&](int off, float lo, float hi) {
        *(float2*)&smem[off] = make_float2(lo, hi);
    };
    auto storebuf = [&](int buf) {
        int a = buf * APLANE + aw;
        st64(a, pa0h.x, pa0h.y);                 st64(a + 4, pa0h.z, pa0h.w);
        st64(a + ASEG, pa1h.x, pa1h.y);          st64(a + ASEG + 4, pa1h.z, pa1h.w);
        int al = ASL_OFF + buf * APLANE + aw;
        st64(al, pa0l.x, pa0l.y);                st64(al + 4, pa0l.z, pa0l.w);
        st64(al + ASEG, pa1l.x, pa1l.y);         st64(al + ASEG + 4, pa1l.z, pa1l.w);
        int b = BSH_OFF + buf * BPLANE + bw;
        st64(b, pbh.x, pbh.y);                   st64(b + 4, pbh.z, pbh.w);
        int bl = BSL_OFF + buf * BPLANE + bw;
        st64(bl, pbl.x, pbl.y);                  st64(bl + 4, pbl.z, pbl.w);
    };

    f32x4 acc1[4][2] = {};
    f32x4 acc2[4][2] = {};

    loadregs(0);
    storebuf(0);
    const int nIter = K >> 5;
    int cur = 0;
    for (int it = 0; it < nIter; ++it) {
        if (it + 1 < nIter) loadregs((it + 1) << 5);
        lds_barrier();
        const int abase = cur * APLANE + (wm + l16) * ASTRIDE + (quad << 3);
        const int bbase = BSH_OFF + cur * BPLANE + (wn + l16) * ASTRIDE + (quad << 3);
        f16x8 fah[4], fal[4], fgh[2], fgl[2];
#pragma unroll
        for (int f = 0; f < 4; ++f) {
            int o = abase + f * (16 * ASTRIDE);
            ((f16x4*)&fah[f])[0] = *(const f16x4*)&smem[o];
            ((f16x4*)&fah[f])[1] = *(const f16x4*)&smem[o + 4];
            ((f16x4*)&fal[f])[0] = *(const f16x4*)&smem[o + ASL_OFF];
            ((f16x4*)&fal[f])[1] = *(const f16x4*)&smem[o + ASL_OFF + 4];
        }
#pragma unroll
        for (int g = 0; g < 2; ++g) {
            int o = bbase + g * (16 * ASTRIDE);
            ((f16x4*)&fgh[g])[0] = *(const f16x4*)&smem[o];
            ((f16x4*)&fgh[g])[1] = *(const f16x4*)&smem[o + 4];
            ((f16x4*)&fgl[g])[0] = *(const f16x4*)&smem[o + (BSL_OFF - BSH_OFF)];
            ((f16x4*)&fgl[g])[1] = *(const f16x4*)&smem[o + (BSL_OFF - BSH_OFF) + 4];
        }
#pragma unroll
        for (int f = 0; f < 4; ++f)
#pragma unroll
            for (int g = 0; g < 2; ++g)
                acc2[f][g] = __builtin_amdgcn_mfma_f32_16x16x32_f16(fah[f], fgl[g], acc2[f][g], 0, 0, 0);
#pragma unroll
        for (int f = 0; f < 4; ++f)
#pragma unroll
            for (int g = 0; g < 2; ++g)
                acc2[f][g] = __builtin_amdgcn_mfma_f32_16x16x32_f16(fal[f], fgh[g], acc2[f][g], 0, 0, 0);
#pragma unroll
        for (int f = 0; f < 4; ++f)
#pragma unroll
            for (int g = 0; g < 2; ++g)
                acc1[f][g] = __builtin_amdgcn_mfma_f32_16x16x32_f16(fah[f], fgh[g], acc1[f][g], 0, 0, 0);
        if (it + 1 < nIter) storebuf(cur ^ 1);
        cur ^= 1;
    }

    float bv[2];
    bv[0] = bias[n0 + wn + l16];
    bv[1] = bias[n0 + wn + 16 + l16];

    if (MODE == 1) {
        __syncthreads();
        // planes (halves): hi @0, lo @9216; row stride 72, 128 rows x 64 cols
#pragma unroll
        for (int f = 0; f < 4; ++f)
#pragma unroll
            for (int g = 0; g < 2; ++g)
#pragma unroll
                for (int r = 0; r < 4; ++r) {
                    int rm = wm + f * 16 + quad * 4 + r;
                    int cn = wn + g * 16 + l16;
                    float v = acc1[f][g][r] + acc2[f][g][r] * LO_INV + bv[g];
                    v = 0.5f * v * (1.0f + erff(v * 0.70710678118654752f));
                    half_t hh = (half_t)v;
                    smem[rm * 72 + cn] = hh;
                    smem[9216 + rm * 72 + cn] = (half_t)((v - (float)hh) * LO_SCALE);
                }
        __syncthreads();
#pragma unroll
        for (int s = 0; s < 4; ++s) {
            int idx = tid + (s << 8);
            int row = idx >> 3, c8 = (idx & 7) << 3;
            long go = (long)(m0 + row) * N + n0 + c8;
            *(float4*)(Ch + go) = *(const float4*)&smem[row * 72 + c8];
            *(float4*)(Cl + go) = *(const float4*)&smem[9216 + row * 72 + c8];
        }
    } else {
#pragma unroll
        for (int f = 0; f < 4; ++f)
#pragma unroll
            for (int g = 0; g < 2; ++g)
#pragma unroll
                for (int r = 0; r < 4; ++r) {
                    long row = m0 + wm + f * 16 + quad * 4 + r;
                    int col = n0 + wn + g * 16 + l16;
                    float v = acc1[f][g][r] + acc2[f][g][r] * LO_INV + bv[g];
                    long o = row * N + col;
                    if (MODE == 2) v += res[o];
                    Cf[o] = v;
                }
    }
}

// ---------------------------------------------------------------------------
// Fused out-conv (pointwise, C=8) + nearest-embedding argmin over K=8192
// ---------------------------------------------------------------------------
__global__ __launch_bounds__(256) void k_outconv_argmin(
    const float* __restrict__ h, const float* __restrict__ ow,
    const float* __restrict__ ob, const float* __restrict__ emb,
    int* __restrict__ outIdx) {
    __shared__ float hs[16][H_ + 1];
    __shared__ float zs[16][8];
    __shared__ float es[16 * 516];
    __shared__ float rb[16][16];
    __shared__ int ri[16][16];
    const int tid = threadIdx.x;
    const int row0 = blockIdx.x << 4;

    for (int i = tid; i < 16 * (H_ / 4); i += 256) {
        int r = i / 96;
        int c4 = (i % 96) << 2;
        float4 v = *(const float4*)&h[((long)(row0 + r)) * H_ + c4];
        hs[r][c4] = v.x; hs[r][c4 + 1] = v.y; hs[r][c4 + 2] = v.z; hs[r][c4 + 3] = v.w;
    }
    __syncthreads();

    if (tid < 128) {
        int r = tid & 15, c = tid >> 4;
        float acc = ob[c];
        const float* wc = ow + c * H_;
        for (int j = 0; j < H_; ++j) acc = fmaf(hs[r][j], wc[j], acc);
        zs[r][c] = acc;
    }
    __syncthreads();

    const int r = tid & 15;
    const int sl = tid >> 4;
    float z0 = zs[r][0], z1 = zs[r][1], z2 = zs[r][2], z3 = zs[r][3];
    float z4 = zs[r][4], z5 = zs[r][5], z6 = zs[r][6], z7 = zs[r][7];
    float best = 3.4e38f;
    int bi = 0;

    for (int ch = 0; ch < 8; ++ch) {
        __syncthreads();
        for (int i = tid; i < 2048; i += 256) {
            int e = i >> 1;
            int half = (i & 1) << 2;
            float4 src = *(const float4*)&emb[(((long)(ch << 10)) + e) * 8 + half];
            *(float4*)&es[(e >> 6) * 516 + ((e & 63) << 3) + half] = src;
        }
        __syncthreads();
        const float* ep = es + sl * 516;
        int gbase = (ch << 10) + (sl << 6);
#pragma unroll 4
        for (int j = 0; j < 64; ++j) {
            float4 e0 = *(const float4*)(ep + (j << 3));
            float4 e1 = *(const float4*)(ep + (j << 3) + 4);
            float t, d;
            t = e0.x - z0; d = t * t;
            t = e0.y - z1; d = fmaf(t, t, d);
            t = e0.z - z2; d = fmaf(t, t, d);
            t = e0.w - z3; d = fmaf(t, t, d);
            t = e1.x - z4; d = fmaf(t, t, d);
            t = e1.y - z5; d = fmaf(t, t, d);
            t = e1.z - z6; d = fmaf(t, t, d);
            t = e1.w - z7; d = fmaf(t, t, d);
            if (d < best) { best = d; bi = gbase + j; }
        }
    }
    rb[r][sl] = best;
    ri[r][sl] = bi;
    __syncthreads();
    if (sl == 0) {
        float bb = rb[r][0];
        int bbi = ri[r][0];
#pragma unroll
        for (int s2 = 1; s2 < 16; ++s2) {
            float v = rb[r][s2];
            int i2 = ri[r][s2];
            if (v < bb || (v == bb && i2 < bbi)) { bb = v; bbi = i2; }
        }
        outIdx[row0 + r] = bbi;
    }
}

// ---------------------------------------------------------------------------
// host launcher
// ---------------------------------------------------------------------------
extern "C" void kernel_launch(void* const* d_in, const int* in_sizes, int n_in,
                              void* d_out, int out_size, void* d_ws, size_t ws_size,
                              hipStream_t stream) {
    const float* x        = (const float*)d_in[0];
    const float* enc_w    = (const float*)d_in[1];
    const float* enc_b    = (const float*)d_in[2];
    const float* enc_ln_g = (const float*)d_in[3];
    const float* enc_ln_b = (const float*)d_in[4];
    const float* blk_dw_w = (const float*)d_in[5];
    const float* blk_dw_b = (const float*)d_in[6];
    const float* blk_ln_g = (const float*)d_in[7];
    const float* blk_ln_b = (const float*)d_in[8];
    const float* blk_w1   = (const float*)d_in[9];
    const float* blk_b1   = (const float*)d_in[10];
    const float* blk_w2   = (const float*)d_in[11];
    const float* blk_b2   = (const float*)d_in[12];
    const float* out_w    = (const float*)d_in[13];
    const float* out_b    = (const float*)d_in[14];
    const float* emb      = (const float*)d_in[15];
    int* out = (int*)d_out;

    char* base = (char*)d_ws;
    float*  h    = (float*)base;                       // 25165824 B
    half_t* tmph = (half_t*)(base + 25165824);         // 12582912 B
    half_t* tmpl = (half_t*)(base + 37748736);         // 12582912 B
    half_t* ht4h = (half_t*)(base + 50331648);         // 50331648 B
    half_t* ht4l = (half_t*)(base + 100663296);        // 50331648 B
    half_t* ench = (half_t*)(base + 150994944);        // 2752512 B
    half_t* encl = (half_t*)(base + 153747456);        // 2752512 B
    half_t* w1h  = (half_t*)(base + 156499968);        // 7077888 B
    half_t* w1l  = (half_t*)(base + 163577856);        // 7077888 B
    half_t* w2h  = (half_t*)(base + 170655744);        // 7077888 B
    half_t* w2l  = (half_t*)(base + 177733632);        // 7077888 B
    // x hi/lo alias the ht4 region (dead until first GEMM1)
    half_t* xh = ht4h;                                  // 16777216 B
    half_t* xl = (half_t*)(base + 50331648 + 16777216); // 16777216 B

    k_split<<<(8388608 + 255) / 256, 256, 0, stream>>>(x, xh, xl, 8388608L);
    k_split<<<(3538944 + 255) / 256, 256, 0, stream>>>(blk_w1, w1h, w1l, 3538944L);
    k_split<<<(3538944 + 255) / 256, 256, 0, stream>>>(blk_w2, w2h, w2l, 3538944L);
    k_split_encw<<<(H_ * 3584 + 255) / 256, 256, 0, stream>>>(enc_w, ench, encl);

    // encoder conv (im2row MFMA GEMM) -> h, then in-place LN
    // grid x=m (m-major): per XCD, B n-slice (~0.9 MB) stays L2-resident
    k_mgemm<0><<<dim3(128, 6), 256, 0, stream>>>(xh, xl, ench, encl, enc_b,
                                                 nullptr, h, nullptr, nullptr,
                                                 H_, 3584);
    k_ln<<<BT_, 64, 0, stream>>>(h, h, enc_ln_g, enc_ln_b);

    for (int i = 0; i < 6; ++i) {
        k_dwconv_ln<<<BT_ / 4, 256, 0, stream>>>(h, tmph, tmpl, blk_dw_w + i * H_ * 7,
                                                 blk_dw_b + i * H_, blk_ln_g + i * H_,
                                                 blk_ln_b + i * H_);
        k_mgemm<1><<<dim3(24, 128), 256, 0, stream>>>(
            tmph, tmpl, w1h + (long)i * 589824, w1l + (long)i * 589824,
            blk_b1 + i * H4_, nullptr, nullptr, ht4h, ht4l, H4_, H_);
        k_mgemm<2><<<dim3(6, 128), 256, 0, stream>>>(
            ht4h, ht4l, w2h + (long)i * 589824, w2l + (long)i * 589824,
            blk_b2 + i * H_, h, h, nullptr, nullptr, H_, H4_);
    }

    k_outconv_argmin<<<BT_ / 16, 256, 0, stream>>>(h, out_w, out_b, emb, out);
}

// Round 7
// 1886.177 us; speedup vs baseline: 1.0596x; 1.0596x over previous
//
#include <hip/hip_runtime.h>
#include <math.h>

#define T_   2048
#define DIN  512
#define H_   384
#define H4_  1536
#define BT_  16384

typedef _Float16 half_t;
typedef _Float16 f16x8 __attribute__((ext_vector_type(8)));
typedef float f32x4 __attribute__((ext_vector_type(4)));

#define LO_SCALE 2048.0f
#define LO_INV   4.8828125e-4f

// LDS geometry: row stride 32 halves (64 B = 4 granules of 16 B), XOR swizzle
// granule ^= (row & 3). Stores (granule=tid&3) and frag reads (granule=quad)
// both hit every bank-group exactly 2x per 16 lanes -> conflict-free (2-way
// aliasing is free on gfx950). No padding; b128 ops throughout.
#define APLANE 4096     // 128 rows * 32 halves
#define BPLANE 2048     // 64 rows * 32 halves
#define ASL_OFF 8192    // 2 bufs * APLANE
#define BSH_OFF 16384
#define BSL_OFF 20480
#define SMEM_H  24576   // halves (48 KB)

// lgkm-only barrier: prefetched global->VGPR loads stay in flight across it.
__device__ __forceinline__ void lds_barrier() {
    asm volatile("s_waitcnt lgkmcnt(0)\n\ts_barrier" ::: "memory");
}

__device__ __forceinline__ void split2(float v, half_t* hi, half_t* lo) {
    half_t h = (half_t)v;
    *hi = h;
    *lo = (half_t)((v - (float)h) * LO_SCALE);
}

// ---------------------------------------------------------------------------
// fp32 -> (hi, lo*2048) fp16 element-wise split
// ---------------------------------------------------------------------------
__global__ void k_split(const float* __restrict__ in, half_t* __restrict__ hi,
                        half_t* __restrict__ lo, long n) {
    long i = (long)blockIdx.x * 256 + threadIdx.x;
    if (i >= n) return;
    split2(in[i], hi + i, lo + i);
}

// enc_w [H][DIN][7] -> [H][tap*512+i] hi/lo
__global__ void k_split_encw(const float* __restrict__ in, half_t* __restrict__ hi,
                             half_t* __restrict__ lo) {
    int idx = blockIdx.x * 256 + threadIdx.x;
    if (idx >= H_ * 3584) return;
    int n = idx / 3584;
    int r = idx % 3584;
    int tap = r >> 9, i = r & 511;
    split2(in[n * 3584 + i * 7 + tap], hi + idx, lo + idx);
}

// ---------------------------------------------------------------------------
// Row-wise LayerNorm over H=384 (fp32 in/out, in-place safe), one wave per row
// ---------------------------------------------------------------------------
__global__ void k_ln(const float* __restrict__ in, float* __restrict__ out,
                     const float* __restrict__ g, const float* __restrict__ b) {
    int row = blockIdx.x;
    int lane = threadIdx.x;
    const float* ir = in + (long)row * H_;
    float v[6];
    float s = 0.f;
#pragma unroll
    for (int j = 0; j < 6; ++j) { v[j] = ir[lane + (j << 6)]; s += v[j]; }
#pragma unroll
    for (int o = 32; o > 0; o >>= 1) s += __shfl_down(s, o, 64);
    s = __shfl(s, 0, 64);
    float mean = s * (1.f / 384.f);
    float q = 0.f;
#pragma unroll
    for (int j = 0; j < 6; ++j) { float d = v[j] - mean; q += d * d; }
#pragma unroll
    for (int o = 32; o > 0; o >>= 1) q += __shfl_down(q, o, 64);
    q = __shfl(q, 0, 64);
    float rstd = rsqrtf(q * (1.f / 384.f) + 1e-5f);
    float* orow = out + (long)row * H_;
#pragma unroll
    for (int j = 0; j < 6; ++j) {
        int c = lane + (j << 6);
        orow[c] = (v[j] - mean) * rstd * g[c] + b[c];
    }
}

// ---------------------------------------------------------------------------
// Fused depthwise conv (k=7, pad=3) + LayerNorm; emits fp16 hi/lo for GEMM1
// 4 rows per block (one per wave) so the 7-tap t-overlap is L1-resident.
// ---------------------------------------------------------------------------
__global__ __launch_bounds__(256) void k_dwconv_ln(
    const float* __restrict__ h, half_t* __restrict__ oh,
    half_t* __restrict__ ol,
    const float* __restrict__ w, const float* __restrict__ wb,
    const float* __restrict__ g, const float* __restrict__ gb) {
    int row = (blockIdx.x << 2) + (threadIdx.x >> 6);
    int b = row >> 11;
    int t = row & 2047;
    int lane = threadIdx.x & 63;
    const float* hb = h + ((long)b * T_) * H_;
    float v[6];
    float s = 0.f;
#pragma unroll
    for (int j = 0; j < 6; ++j) {
        int c = lane + (j << 6);
        float acc = wb[c];
        const float* wc = w + c * 7;
#pragma unroll
        for (int k = 0; k < 7; ++k) {
            int tt = t + k - 3;
            if ((unsigned)tt < (unsigned)T_)
                acc = fmaf(hb[(long)tt * H_ + c], wc[k], acc);
        }
        v[j] = acc;
        s += acc;
    }
#pragma unroll
    for (int o = 32; o > 0; o >>= 1) s += __shfl_down(s, o, 64);
    s = __shfl(s, 0, 64);
    float mean = s * (1.f / 384.f);
    float q = 0.f;
#pragma unroll
    for (int j = 0; j < 6; ++j) { float d = v[j] - mean; q += d * d; }
#pragma unroll
    for (int o = 32; o > 0; o >>= 1) q += __shfl_down(q, o, 64);
    q = __shfl(q, 0, 64);
    float rstd = rsqrtf(q * (1.f / 384.f) + 1e-5f);
    long ro = (long)row * H_;
#pragma unroll
    for (int j = 0; j < 6; ++j) {
        int c = lane + (j << 6);
        float val = (v[j] - mean) * rstd * g[c] + gb[c];
        split2(val, oh + ro + c, ol + ro + c);
    }
}

// ---------------------------------------------------------------------------
// MFMA fp16x3 GEMM: C = A@B^T(+bias...), A [M][K] hi/lo fp16, B [N][K] hi/lo.
// BM=128, BN=64, BK=32; 4 waves, wave tile 64x32 (4x2 frags of 16x16x32).
// lo terms pre-scaled by 2048, accumulated separately, recombined at epilogue.
// XOR-swizzled LDS (see top), double-buffered, one lgkm barrier/iter.
// MODE 0: A = x im2row (K=3584), +bias, fp32 out; grid x=m (B L2-resident/XCD)
// MODE 1: +bias, exact GELU, fp16 hi/lo out; grid x=n (A-slice L2 reuse)
// MODE 2: +bias, +res, fp32 out; grid x=n
// ---------------------------------------------------------------------------
template <int MODE>
__global__ __launch_bounds__(256) void k_mgemm(
    const half_t* __restrict__ Ah, const half_t* __restrict__ Al,
    const half_t* __restrict__ Bh, const half_t* __restrict__ Bl,
    const float* __restrict__ bias, const float* __restrict__ res,
    float* __restrict__ Cf, half_t* __restrict__ Ch, half_t* __restrict__ Cl,
    int N, int K) {
    __shared__ __align__(16) half_t smem[SMEM_H];
    const int tid = threadIdx.x;
    const int lane = tid & 63, wid = tid >> 6;
    const int wm = (wid >> 1) << 6, wn = (wid & 1) << 5;
    const int quad = lane >> 4, l16 = lane & 15;
    const int m0 = (MODE == 0 ? blockIdx.x : blockIdx.y) << 7;
    const int n0 = (MODE == 0 ? blockIdx.y : blockIdx.x) << 6;
    const int ar = tid >> 2;          // A row for seg0 (0..63), seg1 = +64
    const int ak = (tid & 3) << 3;    // k offset (halves), granule = tid&3
    const int br = tid >> 2, bk = (tid & 3) << 3;

    long aoff0 = 0, aoff1 = 0;
    int tt0 = 0, tt1 = 0, bq = 0;
    if (MODE == 0) {
        bq = m0 >> 11;
        tt0 = (m0 & 2047) + ar - 3;
        tt1 = tt0 + 64;
    } else {
        aoff0 = (long)(m0 + ar) * K + ak;
        aoff1 = aoff0 + (long)64 * K;
    }
    const long boff = (long)(n0 + br) * K + bk;

    float4 pa0h, pa0l, pa1h, pa1l, pbh, pbl;
    auto loadregs = [&](int k0) {
        if (MODE == 0) {
            int kk = k0 + ak;
            int tap = kk >> 9, ii = kk & 511;
            int ta = tt0 + tap, tb = tt1 + tap;
            pa0h = pa0l = pa1h = pa1l = make_float4(0.f, 0.f, 0.f, 0.f);
            if ((unsigned)ta < 2048u) {
                long o = ((long)bq * 2048 + ta) * 512 + ii;
                pa0h = *(const float4*)(Ah + o);
                pa0l = *(const float4*)(Al + o);
            }
            if ((unsigned)tb < 2048u) {
                long o = ((long)bq * 2048 + tb) * 512 + ii;
                pa1h = *(const float4*)(Ah + o);
                pa1l = *(const float4*)(Al + o);
            }
        } else {
            pa0h = *(const float4*)(Ah + aoff0 + k0);
            pa0l = *(const float4*)(Al + aoff0 + k0);
            pa1h = *(const float4*)(Ah + aoff1 + k0);
            pa1l = *(const float4*)(Al + aoff1 + k0);
        }
        pbh = *(const float4*)(Bh + boff + k0);
        pbl = *(const float4*)(Bl + boff + k0);
    };
    // swizzled staging offsets (seg1 row = ar+64 has same (row&3) -> same swizzle)
    const int aw = ar * 32 + ((((tid & 3) ^ ar) & 3) << 3);
    const int bw = br * 32 + ((((tid & 3) ^ br) & 3) << 3);
    auto storebuf = [&](int buf) {
        int a = buf * APLANE + aw;
        *(float4*)&smem[a] = pa0h;
        *(float4*)&smem[a + 2048] = pa1h;
        int al = ASL_OFF + buf * APLANE + aw;
        *(float4*)&smem[al] = pa0l;
        *(float4*)&smem[al + 2048] = pa1l;
        *(float4*)&smem[BSH_OFF + buf * BPLANE + bw] = pbh;
        *(float4*)&smem[BSL_OFF + buf * BPLANE + bw] = pbl;
    };

    f32x4 acc1[4][2] = {};
    f32x4 acc2[4][2] = {};

    loadregs(0);
    storebuf(0);
    const int nIter = K >> 5;
    int cur = 0;
    const int sw = ((quad ^ l16) & 3) << 3;   // read-side swizzle
    for (int it = 0; it < nIter; ++it) {
        if (it + 1 < nIter) loadregs((it + 1) << 5);
        lds_barrier();
        const int ab = cur * APLANE + (wm + l16) * 32 + sw;
        const int bb = BSH_OFF + cur * BPLANE + (wn + l16) * 32 + sw;
        f16x8 fah[4], fal[4], fgh[2], fgl[2];
#pragma unroll
        for (int f = 0; f < 4; ++f) {
            fah[f] = *(const f16x8*)&smem[ab + f * 512];
            fal[f] = *(const f16x8*)&smem[ab + ASL_OFF + f * 512];
        }
#pragma unroll
        for (int g = 0; g < 2; ++g) {
            fgh[g] = *(const f16x8*)&smem[bb + g * 512];
            fgl[g] = *(const f16x8*)&smem[bb + 4096 + g * 512];
        }
#pragma unroll
        for (int f = 0; f < 4; ++f)
#pragma unroll
            for (int g = 0; g < 2; ++g)
                acc2[f][g] = __builtin_amdgcn_mfma_f32_16x16x32_f16(fah[f], fgl[g], acc2[f][g], 0, 0, 0);
#pragma unroll
        for (int f = 0; f < 4; ++f)
#pragma unroll
            for (int g = 0; g < 2; ++g)
                acc2[f][g] = __builtin_amdgcn_mfma_f32_16x16x32_f16(fal[f], fgh[g], acc2[f][g], 0, 0, 0);
#pragma unroll
        for (int f = 0; f < 4; ++f)
#pragma unroll
            for (int g = 0; g < 2; ++g)
                acc1[f][g] = __builtin_amdgcn_mfma_f32_16x16x32_f16(fah[f], fgh[g], acc1[f][g], 0, 0, 0);
        if (it + 1 < nIter) storebuf(cur ^ 1);
        cur ^= 1;
    }

    float bv[2];
    bv[0] = bias[n0 + wn + l16];
    bv[1] = bias[n0 + wn + 16 + l16];

    if (MODE == 1) {
        __syncthreads();
        // planes (halves): hi @0, lo @9216; row stride 72, 128 rows x 64 cols
#pragma unroll
        for (int f = 0; f < 4; ++f)
#pragma unroll
            for (int g = 0; g < 2; ++g)
#pragma unroll
                for (int r = 0; r < 4; ++r) {
                    int rm = wm + f * 16 + quad * 4 + r;
                    int cn = wn + g * 16 + l16;
                    float v = acc1[f][g][r] + acc2[f][g][r] * LO_INV + bv[g];
                    v = 0.5f * v * (1.0f + erff(v * 0.70710678118654752f));
                    half_t hh = (half_t)v;
                    smem[rm * 72 + cn] = hh;
                    smem[9216 + rm * 72 + cn] = (half_t)((v - (float)hh) * LO_SCALE);
                }
        __syncthreads();
#pragma unroll
        for (int s = 0; s < 4; ++s) {
            int idx = tid + (s << 8);
            int row = idx >> 3, c8 = (idx & 7) << 3;
            long go = (long)(m0 + row) * N + n0 + c8;
            *(float4*)(Ch + go) = *(const float4*)&smem[row * 72 + c8];
            *(float4*)(Cl + go) = *(const float4*)&smem[9216 + row * 72 + c8];
        }
    } else {
#pragma unroll
        for (int f = 0; f < 4; ++f)
#pragma unroll
            for (int g = 0; g < 2; ++g)
#pragma unroll
                for (int r = 0; r < 4; ++r) {
                    long row = m0 + wm + f * 16 + quad * 4 + r;
                    int col = n0 + wn + g * 16 + l16;
                    float v = acc1[f][g][r] + acc2[f][g][r] * LO_INV + bv[g];
                    long o = row * N + col;
                    if (MODE == 2) v += res[o];
                    Cf[o] = v;
                }
    }
}

// ---------------------------------------------------------------------------
// Fused out-conv (pointwise, C=8) + nearest-embedding argmin over K=8192
// ---------------------------------------------------------------------------
__global__ __launch_bounds__(256) void k_outconv_argmin(
    const float* __restrict__ h, const float* __restrict__ ow,
    const float* __restrict__ ob, const float* __restrict__ emb,
    int* __restrict__ outIdx) {
    __shared__ float hs[16][H_ + 1];
    __shared__ float zs[16][8];
    __shared__ float es[16 * 516];
    __shared__ float rb[16][16];
    __shared__ int ri[16][16];
    const int tid = threadIdx.x;
    const int row0 = blockIdx.x << 4;

    for (int i = tid; i < 16 * (H_ / 4); i += 256) {
        int r = i / 96;
        int c4 = (i % 96) << 2;
        float4 v = *(const float4*)&h[((long)(row0 + r)) * H_ + c4];
        hs[r][c4] = v.x; hs[r][c4 + 1] = v.y; hs[r][c4 + 2] = v.z; hs[r][c4 + 3] = v.w;
    }
    __syncthreads();

    if (tid < 128) {
        int r = tid & 15, c = tid >> 4;
        float acc = ob[c];
        const float* wc = ow + c * H_;
        for (int j = 0; j < H_; ++j) acc = fmaf(hs[r][j], wc[j], acc);
        zs[r][c] = acc;
    }
    __syncthreads();

    const int r = tid & 15;
    const int sl = tid >> 4;
    float z0 = zs[r][0], z1 = zs[r][1], z2 = zs[r][2], z3 = zs[r][3];
    float z4 = zs[r][4], z5 = zs[r][5], z6 = zs[r][6], z7 = zs[r][7];
    float best = 3.4e38f;
    int bi = 0;

    for (int ch = 0; ch < 8; ++ch) {
        __syncthreads();
        for (int i = tid; i < 2048; i += 256) {
            int e = i >> 1;
            int half = (i & 1) << 2;
            float4 src = *(const float4*)&emb[(((long)(ch << 10)) + e) * 8 + half];
            *(float4*)&es[(e >> 6) * 516 + ((e & 63) << 3) + half] = src;
        }
        __syncthreads();
        const float* ep = es + sl * 516;
        int gbase = (ch << 10) + (sl << 6);
#pragma unroll 4
        for (int j = 0; j < 64; ++j) {
            float4 e0 = *(const float4*)(ep + (j << 3));
            float4 e1 = *(const float4*)(ep + (j << 3) + 4);
            float t, d;
            t = e0.x - z0; d = t * t;
            t = e0.y - z1; d = fmaf(t, t, d);
            t = e0.z - z2; d = fmaf(t, t, d);
            t = e0.w - z3; d = fmaf(t, t, d);
            t = e1.x - z4; d = fmaf(t, t, d);
            t = e1.y - z5; d = fmaf(t, t, d);
            t = e1.z - z6; d = fmaf(t, t, d);
            t = e1.w - z7; d = fmaf(t, t, d);
            if (d < best) { best = d; bi = gbase + j; }
        }
    }
    rb[r][sl] = best;
    ri[r][sl] = bi;
    __syncthreads();
    if (sl == 0) {
        float bb = rb[r][0];
        int bbi = ri[r][0];
#pragma unroll
        for (int s2 = 1; s2 < 16; ++s2) {
            float v = rb[r][s2];
            int i2 = ri[r][s2];
            if (v < bb || (v == bb && i2 < bbi)) { bb = v; bbi = i2; }
        }
        outIdx[row0 + r] = bbi;
    }
}

// ---------------------------------------------------------------------------
// host launcher
// ---------------------------------------------------------------------------
extern "C" void kernel_launch(void* const* d_in, const int* in_sizes, int n_in,
                              void* d_out, int out_size, void* d_ws, size_t ws_size,
                              hipStream_t stream) {
    const float* x        = (const float*)d_in[0];
    const float* enc_w    = (const float*)d_in[1];
    const float* enc_b    = (const float*)d_in[2];
    const float* enc_ln_g = (const float*)d_in[3];
    const float* enc_ln_b = (const float*)d_in[4];
    const float* blk_dw_w = (const float*)d_in[5];
    const float* blk_dw_b = (const float*)d_in[6];
    const float* blk_ln_g = (const float*)d_in[7];
    const float* blk_ln_b = (const float*)d_in[8];
    const float* blk_w1   = (const float*)d_in[9];
    const float* blk_b1   = (const float*)d_in[10];
    const float* blk_w2   = (const float*)d_in[11];
    const float* blk_b2   = (const float*)d_in[12];
    const float* out_w    = (const float*)d_in[13];
    const float* out_b    = (const float*)d_in[14];
    const float* emb      = (const float*)d_in[15];
    int* out = (int*)d_out;

    char* base = (char*)d_ws;
    float*  h    = (float*)base;                       // 25165824 B
    half_t* tmph = (half_t*)(base + 25165824);         // 12582912 B
    half_t* tmpl = (half_t*)(base + 37748736);         // 12582912 B
    half_t* ht4h = (half_t*)(base + 50331648);         // 50331648 B
    half_t* ht4l = (half_t*)(base + 100663296);        // 50331648 B
    half_t* ench = (half_t*)(base + 150994944);        // 2752512 B
    half_t* encl = (half_t*)(base + 153747456);        // 2752512 B
    half_t* w1h  = (half_t*)(base + 156499968);        // 7077888 B
    half_t* w1l  = (half_t*)(base + 163577856);        // 7077888 B
    half_t* w2h  = (half_t*)(base + 170655744);        // 7077888 B
    half_t* w2l  = (half_t*)(base + 177733632);        // 7077888 B
    // x hi/lo alias the ht4 region (dead until first GEMM1)
    half_t* xh = ht4h;                                  // 16777216 B
    half_t* xl = (half_t*)(base + 50331648 + 16777216); // 16777216 B

    k_split<<<(8388608 + 255) / 256, 256, 0, stream>>>(x, xh, xl, 8388608L);
    k_split<<<(3538944 + 255) / 256, 256, 0, stream>>>(blk_w1, w1h, w1l, 3538944L);
    k_split<<<(3538944 + 255) / 256, 256, 0, stream>>>(blk_w2, w2h, w2l, 3538944L);
    k_split_encw<<<(H_ * 3584 + 255) / 256, 256, 0, stream>>>(enc_w, ench, encl);

    // encoder conv (im2row MFMA GEMM) -> h, then in-place LN
    // grid x=m (m-major): per XCD, B n-slice (~0.9 MB) stays L2-resident
    k_mgemm<0><<<dim3(128, 6), 256, 0, stream>>>(xh, xl, ench, encl, enc_b,
                                                 nullptr, h, nullptr, nullptr,
                                                 H_, 3584);
    k_ln<<<BT_, 64, 0, stream>>>(h, h, enc_ln_g, enc_ln_b);

    for (int i = 0; i < 6; ++i) {
        k_dwconv_ln<<<BT_ / 4, 256, 0, stream>>>(h, tmph, tmpl, blk_dw_w + i * H_ * 7,
                                                 blk_dw_b + i * H_, blk_ln_g + i * H_,
                                                 blk_ln_b + i * H_);
        k_mgemm<1><<<dim3(24, 128), 256, 0, stream>>>(
            tmph, tmpl, w1h + (long)i * 589824, w1l + (long)i * 589824,
            blk_b1 + i * H4_, nullptr, nullptr, ht4h, ht4l, H4_, H_);
        k_mgemm<2><<<dim3(6, 128), 256, 0, stream>>>(
            ht4h, ht4l, w2h + (long)i * 589824, w2l + (long)i * 589824,
            blk_b2 + i * H_, h, h, nullptr, nullptr, H_, H4_);
    }

    k_outconv_argmin<<<BT_ / 16, 256, 0, stream>>>(h, out_w, out_b, emb, out);
}

// Round 8
// 1849.704 us; speedup vs baseline: 1.0805x; 1.0197x over previous
//
#include <hip/hip_runtime.h>
#include <math.h>

#define T_   2048
#define DIN  512
#define H_   384
#define H4_  1536
#define BT_  16384

typedef _Float16 half_t;
typedef _Float16 f16x8 __attribute__((ext_vector_type(8)));
typedef float f32x4 __attribute__((ext_vector_type(4)));

#define LO_SCALE 2048.0f
#define LO_INV   4.8828125e-4f

// LDS geometry: row stride 32 halves (64 B = 4 granules of 16 B), XOR swizzle
// granule ^= (row & 3); conflict-free b128 stores and frag reads (<=2-way).
// BM=BN=128, BK=32, hi+lo planes, double-buffered: 64 KB.
#define APLANE 4096     // 128 rows * 32 halves
#define ASL_OFF 8192    // 2 bufs * APLANE
#define BSH_OFF 16384
#define BSL_OFF 24576
#define SMEM_H  32768   // halves (64 KB)

// lgkm-only barrier: prefetched global->VGPR loads stay in flight across it.
__device__ __forceinline__ void lds_barrier() {
    asm volatile("s_waitcnt lgkmcnt(0)\n\ts_barrier" ::: "memory");
}

__device__ __forceinline__ void split2(float v, half_t* hi, half_t* lo) {
    half_t h = (half_t)v;
    *hi = h;
    *lo = (half_t)((v - (float)h) * LO_SCALE);
}

// ---------------------------------------------------------------------------
// fp32 -> (hi, lo*2048) fp16 element-wise split
// ---------------------------------------------------------------------------
__global__ void k_split(const float* __restrict__ in, half_t* __restrict__ hi,
                        half_t* __restrict__ lo, long n) {
    long i = (long)blockIdx.x * 256 + threadIdx.x;
    if (i >= n) return;
    split2(in[i], hi + i, lo + i);
}

// enc_w [H][DIN][7] -> [H][tap*512+i] hi/lo
__global__ void k_split_encw(const float* __restrict__ in, half_t* __restrict__ hi,
                             half_t* __restrict__ lo) {
    int idx = blockIdx.x * 256 + threadIdx.x;
    if (idx >= H_ * 3584) return;
    int n = idx / 3584;
    int r = idx % 3584;
    int tap = r >> 9, i = r & 511;
    split2(in[n * 3584 + i * 7 + tap], hi + idx, lo + idx);
}

// ---------------------------------------------------------------------------
// Row-wise LayerNorm over H=384 (fp32 in/out, in-place safe), one wave per row
// ---------------------------------------------------------------------------
__global__ void k_ln(const float* __restrict__ in, float* __restrict__ out,
                     const float* __restrict__ g, const float* __restrict__ b) {
    int row = blockIdx.x;
    int lane = threadIdx.x;
    const float* ir = in + (long)row * H_;
    float v[6];
    float s = 0.f;
#pragma unroll
    for (int j = 0; j < 6; ++j) { v[j] = ir[lane + (j << 6)]; s += v[j]; }
#pragma unroll
    for (int o = 32; o > 0; o >>= 1) s += __shfl_down(s, o, 64);
    s = __shfl(s, 0, 64);
    float mean = s * (1.f / 384.f);
    float q = 0.f;
#pragma unroll
    for (int j = 0; j < 6; ++j) { float d = v[j] - mean; q += d * d; }
#pragma unroll
    for (int o = 32; o > 0; o >>= 1) q += __shfl_down(q, o, 64);
    q = __shfl(q, 0, 64);
    float rstd = rsqrtf(q * (1.f / 384.f) + 1e-5f);
    float* orow = out + (long)row * H_;
#pragma unroll
    for (int j = 0; j < 6; ++j) {
        int c = lane + (j << 6);
        orow[c] = (v[j] - mean) * rstd * g[c] + b[c];
    }
}

// ---------------------------------------------------------------------------
// Fused depthwise conv (k=7, pad=3) + LayerNorm; emits fp16 hi/lo for GEMM1
// 4 rows per block (one per wave) so the 7-tap t-overlap is L1-resident.
// ---------------------------------------------------------------------------
__global__ __launch_bounds__(256) void k_dwconv_ln(
    const float* __restrict__ h, half_t* __restrict__ oh,
    half_t* __restrict__ ol,
    const float* __restrict__ w, const float* __restrict__ wb,
    const float* __restrict__ g, const float* __restrict__ gb) {
    int row = (blockIdx.x << 2) + (threadIdx.x >> 6);
    int b = row >> 11;
    int t = row & 2047;
    int lane = threadIdx.x & 63;
    const float* hb = h + ((long)b * T_) * H_;
    float v[6];
    float s = 0.f;
#pragma unroll
    for (int j = 0; j < 6; ++j) {
        int c = lane + (j << 6);
        float acc = wb[c];
        const float* wc = w + c * 7;
#pragma unroll
        for (int k = 0; k < 7; ++k) {
            int tt = t + k - 3;
            if ((unsigned)tt < (unsigned)T_)
                acc = fmaf(hb[(long)tt * H_ + c], wc[k], acc);
        }
        v[j] = acc;
        s += acc;
    }
#pragma unroll
    for (int o = 32; o > 0; o >>= 1) s += __shfl_down(s, o, 64);
    s = __shfl(s, 0, 64);
    float mean = s * (1.f / 384.f);
    float q = 0.f;
#pragma unroll
    for (int j = 0; j < 6; ++j) { float d = v[j] - mean; q += d * d; }
#pragma unroll
    for (int o = 32; o > 0; o >>= 1) q += __shfl_down(q, o, 64);
    q = __shfl(q, 0, 64);
    float rstd = rsqrtf(q * (1.f / 384.f) + 1e-5f);
    long ro = (long)row * H_;
#pragma unroll
    for (int j = 0; j < 6; ++j) {
        int c = lane + (j << 6);
        float val = (v[j] - mean) * rstd * g[c] + gb[c];
        split2(val, oh + ro + c, ol + ro + c);
    }
}

// ---------------------------------------------------------------------------
// MFMA fp16x3 GEMM: C = A@B^T(+bias...), A [M][K] hi/lo fp16, B [N][K] hi/lo.
// BM=128, BN=128, BK=32; 512 threads = 8 waves of 64x32 wave tile
// (4x2 frags of 16x16x32). lo planes pre-scaled by 2048, recombined at end.
// XOR-swizzled LDS, double-buffered, one lgkm barrier/iter.
// MODE 0: A = x im2row (K=3584), +bias, fp32 out; grid x=m (B L2-resident)
// MODE 1: +bias, exact GELU, fp16 hi/lo out; grid x=n
// MODE 2: +bias, +res, fp32 out; grid x=n
// ---------------------------------------------------------------------------
template <int MODE>
__global__ __launch_bounds__(512) void k_mgemm(
    const half_t* __restrict__ Ah, const half_t* __restrict__ Al,
    const half_t* __restrict__ Bh, const half_t* __restrict__ Bl,
    const float* __restrict__ bias, const float* __restrict__ res,
    float* __restrict__ Cf, half_t* __restrict__ Ch, half_t* __restrict__ Cl,
    int N, int K) {
    __shared__ __align__(16) half_t smem[SMEM_H];
    const int tid = threadIdx.x;
    const int lane = tid & 63, wid = tid >> 6;
    const int wm = (wid >> 2) << 6, wn = (wid & 3) << 5;
    const int quad = lane >> 4, l16 = lane & 15;
    const int m0 = (MODE == 0 ? blockIdx.x : blockIdx.y) << 7;
    const int n0 = (MODE == 0 ? blockIdx.y : blockIdx.x) << 7;
    const int ar = tid >> 2;          // staging row 0..127 (A and B)
    const int ak = (tid & 3) << 3;    // k offset (halves), granule = tid&3

    long aoff = 0;
    int tt0 = 0, bq = 0;
    if (MODE == 0) {
        bq = m0 >> 11;
        tt0 = (m0 & 2047) + ar - 3;
    } else {
        aoff = (long)(m0 + ar) * K + ak;
    }
    const long boff = (long)(n0 + ar) * K + ak;

    float4 pAh, pAl, pBh, pBl;
    auto loadregs = [&](int k0) {
        if (MODE == 0) {
            int kk = k0 + ak;
            int tap = kk >> 9, ii = kk & 511;
            int ta = tt0 + tap;
            pAh = pAl = make_float4(0.f, 0.f, 0.f, 0.f);
            if ((unsigned)ta < 2048u) {
                long o = ((long)bq * 2048 + ta) * 512 + ii;
                pAh = *(const float4*)(Ah + o);
                pAl = *(const float4*)(Al + o);
            }
        } else {
            pAh = *(const float4*)(Ah + aoff + k0);
            pAl = *(const float4*)(Al + aoff + k0);
        }
        pBh = *(const float4*)(Bh + boff + k0);
        pBl = *(const float4*)(Bl + boff + k0);
    };
    // swizzled staging offset: one 16B granule per thread per plane
    const int aw = ar * 32 + ((((tid & 3) ^ ar) & 3) << 3);
    auto storebuf = [&](int buf) {
        int a = buf * APLANE + aw;
        *(float4*)&smem[a] = pAh;
        *(float4*)&smem[a + ASL_OFF] = pAl;
        *(float4*)&smem[a + BSH_OFF] = pBh;
        *(float4*)&smem[a + BSL_OFF] = pBl;
    };

    f32x4 acc1[4][2] = {};
    f32x4 acc2[4][2] = {};

    loadregs(0);
    storebuf(0);
    const int nIter = K >> 5;
    int cur = 0;
    const int sw = ((quad ^ l16) & 3) << 3;   // read-side swizzle
    for (int it = 0; it < nIter; ++it) {
        if (it + 1 < nIter) loadregs((it + 1) << 5);
        lds_barrier();
        const int ab = cur * APLANE + (wm + l16) * 32 + sw;
        const int bb = BSH_OFF + cur * APLANE + (wn + l16) * 32 + sw;
        f16x8 fah[4], fal[4], fgh[2], fgl[2];
#pragma unroll
        for (int f = 0; f < 4; ++f) {
            fah[f] = *(const f16x8*)&smem[ab + f * 512];
            fal[f] = *(const f16x8*)&smem[ab + ASL_OFF + f * 512];
        }
#pragma unroll
        for (int g = 0; g < 2; ++g) {
            fgh[g] = *(const f16x8*)&smem[bb + g * 512];
            fgl[g] = *(const f16x8*)&smem[bb + ASL_OFF + g * 512];
        }
#pragma unroll
        for (int f = 0; f < 4; ++f)
#pragma unroll
            for (int g = 0; g < 2; ++g)
                acc2[f][g] = __builtin_amdgcn_mfma_f32_16x16x32_f16(fah[f], fgl[g], acc2[f][g], 0, 0, 0);
#pragma unroll
        for (int f = 0; f < 4; ++f)
#pragma unroll
            for (int g = 0; g < 2; ++g)
                acc2[f][g] = __builtin_amdgcn_mfma_f32_16x16x32_f16(fal[f], fgh[g], acc2[f][g], 0, 0, 0);
#pragma unroll
        for (int f = 0; f < 4; ++f)
#pragma unroll
            for (int g = 0; g < 2; ++g)
                acc1[f][g] = __builtin_amdgcn_mfma_f32_16x16x32_f16(fah[f], fgh[g], acc1[f][g], 0, 0, 0);
        if (it + 1 < nIter) storebuf(cur ^ 1);
        cur ^= 1;
    }

    float bv[2];
    bv[0] = bias[n0 + wn + l16];
    bv[1] = bias[n0 + wn + 16 + l16];

    if (MODE == 1) {
        // two passes over 64-col halves; staging planes stride 72:
        // hi @0, lo @9216 (128 rows)
#pragma unroll
        for (int h2 = 0; h2 < 2; ++h2) {
            __syncthreads();
            if (((wid >> 1) & 1) == h2) {
                int cbase = (wid & 1) << 5;
#pragma unroll
                for (int f = 0; f < 4; ++f)
#pragma unroll
                    for (int g = 0; g < 2; ++g)
#pragma unroll
                        for (int r = 0; r < 4; ++r) {
                            int rm = wm + f * 16 + quad * 4 + r;
                            int cn = cbase + g * 16 + l16;
                            float v = acc1[f][g][r] + acc2[f][g][r] * LO_INV + bv[g];
                            v = 0.5f * v * (1.0f + erff(v * 0.70710678118654752f));
                            half_t hh = (half_t)v;
                            smem[rm * 72 + cn] = hh;
                            smem[9216 + rm * 72 + cn] = (half_t)((v - (float)hh) * LO_SCALE);
                        }
            }
            __syncthreads();
            int row = tid >> 2, c16 = (tid & 3) << 4;
            long go = (long)(m0 + row) * N + n0 + (h2 << 6) + c16;
            *(float4*)(Ch + go)     = *(const float4*)&smem[row * 72 + c16];
            *(float4*)(Ch + go + 8) = *(const float4*)&smem[row * 72 + c16 + 8];
            *(float4*)(Cl + go)     = *(const float4*)&smem[9216 + row * 72 + c16];
            *(float4*)(Cl + go + 8) = *(const float4*)&smem[9216 + row * 72 + c16 + 8];
        }
    } else {
#pragma unroll
        for (int f = 0; f < 4; ++f)
#pragma unroll
            for (int g = 0; g < 2; ++g)
#pragma unroll
                for (int r = 0; r < 4; ++r) {
                    long row = m0 + wm + f * 16 + quad * 4 + r;
                    int col = n0 + wn + g * 16 + l16;
                    float v = acc1[f][g][r] + acc2[f][g][r] * LO_INV + bv[g];
                    long o = row * N + col;
                    if (MODE == 2) v += res[o];
                    Cf[o] = v;
                }
    }
}

// ---------------------------------------------------------------------------
// Fused out-conv (pointwise, C=8) + nearest-embedding argmin over K=8192
// ---------------------------------------------------------------------------
__global__ __launch_bounds__(256) void k_outconv_argmin(
    const float* __restrict__ h, const float* __restrict__ ow,
    const float* __restrict__ ob, const float* __restrict__ emb,
    int* __restrict__ outIdx) {
    __shared__ float hs[16][H_ + 1];
    __shared__ float zs[16][8];
    __shared__ float es[16 * 516];
    __shared__ float rb[16][16];
    __shared__ int ri[16][16];
    const int tid = threadIdx.x;
    const int row0 = blockIdx.x << 4;

    for (int i = tid; i < 16 * (H_ / 4); i += 256) {
        int r = i / 96;
        int c4 = (i % 96) << 2;
        float4 v = *(const float4*)&h[((long)(row0 + r)) * H_ + c4];
        hs[r][c4] = v.x; hs[r][c4 + 1] = v.y; hs[r][c4 + 2] = v.z; hs[r][c4 + 3] = v.w;
    }
    __syncthreads();

    if (tid < 128) {
        int r = tid & 15, c = tid >> 4;
        float acc = ob[c];
        const float* wc = ow + c * H_;
        for (int j = 0; j < H_; ++j) acc = fmaf(hs[r][j], wc[j], acc);
        zs[r][c] = acc;
    }
    __syncthreads();

    const int r = tid & 15;
    const int sl = tid >> 4;
    float z0 = zs[r][0], z1 = zs[r][1], z2 = zs[r][2], z3 = zs[r][3];
    float z4 = zs[r][4], z5 = zs[r][5], z6 = zs[r][6], z7 = zs[r][7];
    float best = 3.4e38f;
    int bi = 0;

    for (int ch = 0; ch < 8; ++ch) {
        __syncthreads();
        for (int i = tid; i < 2048; i += 256) {
            int e = i >> 1;
            int half = (i & 1) << 2;
            float4 src = *(const float4*)&emb[(((long)(ch << 10)) + e) * 8 + half];
            *(float4*)&es[(e >> 6) * 516 + ((e & 63) << 3) + half] = src;
        }
        __syncthreads();
        const float* ep = es + sl * 516;
        int gbase = (ch << 10) + (sl << 6);
#pragma unroll 4
        for (int j = 0; j < 64; ++j) {
            float4 e0 = *(const float4*)(ep + (j << 3));
            float4 e1 = *(const float4*)(ep + (j << 3) + 4);
            float t, d;
            t = e0.x - z0; d = t * t;
            t = e0.y - z1; d = fmaf(t, t, d);
            t = e0.z - z2; d = fmaf(t, t, d);
            t = e0.w - z3; d = fmaf(t, t, d);
            t = e1.x - z4; d = fmaf(t, t, d);
            t = e1.y - z5; d = fmaf(t, t, d);
            t = e1.z - z6; d = fmaf(t, t, d);
            t = e1.w - z7; d = fmaf(t, t, d);
            if (d < best) { best = d; bi = gbase + j; }
        }
    }
    rb[r][sl] = best;
    ri[r][sl] = bi;
    __syncthreads();
    if (sl == 0) {
        float bb = rb[r][0];
        int bbi = ri[r][0];
#pragma unroll
        for (int s2 = 1; s2 < 16; ++s2) {
            float v = rb[r][s2];
            int i2 = ri[r][s2];
            if (v < bb || (v == bb && i2 < bbi)) { bb = v; bbi = i2; }
        }
        outIdx[row0 + r] = bbi;
    }
}

// ---------------------------------------------------------------------------
// host launcher
// ---------------------------------------------------------------------------
extern "C" void kernel_launch(void* const* d_in, const int* in_sizes, int n_in,
                              void* d_out, int out_size, void* d_ws, size_t ws_size,
                              hipStream_t stream) {
    const float* x        = (const float*)d_in[0];
    const float* enc_w    = (const float*)d_in[1];
    const float* enc_b    = (const float*)d_in[2];
    const float* enc_ln_g = (const float*)d_in[3];
    const float* enc_ln_b = (const float*)d_in[4];
    const float* blk_dw_w = (const float*)d_in[5];
    const float* blk_dw_b = (const float*)d_in[6];
    const float* blk_ln_g = (const float*)d_in[7];
    const float* blk_ln_b = (const float*)d_in[8];
    const float* blk_w1   = (const float*)d_in[9];
    const float* blk_b1   = (const float*)d_in[10];
    const float* blk_w2   = (const float*)d_in[11];
    const float* blk_b2   = (const float*)d_in[12];
    const float* out_w    = (const float*)d_in[13];
    const float* out_b    = (const float*)d_in[14];
    const float* emb      = (const float*)d_in[15];
    int* out = (int*)d_out;

    char* base = (char*)d_ws;
    float*  h    = (float*)base;                       // 25165824 B
    half_t* tmph = (half_t*)(base + 25165824);         // 12582912 B
    half_t* tmpl = (half_t*)(base + 37748736);         // 12582912 B
    half_t* ht4h = (half_t*)(base + 50331648);         // 50331648 B
    half_t* ht4l = (half_t*)(base + 100663296);        // 50331648 B
    half_t* ench = (half_t*)(base + 150994944);        // 2752512 B
    half_t* encl = (half_t*)(base + 153747456);        // 2752512 B
    half_t* w1h  = (half_t*)(base + 156499968);        // 7077888 B
    half_t* w1l  = (half_t*)(base + 163577856);        // 7077888 B
    half_t* w2h  = (half_t*)(base + 170655744);        // 7077888 B
    half_t* w2l  = (half_t*)(base + 177733632);        // 7077888 B
    // x hi/lo alias the ht4 region (dead until first GEMM1)
    half_t* xh = ht4h;                                  // 16777216 B
    half_t* xl = (half_t*)(base + 50331648 + 16777216); // 16777216 B

    k_split<<<(8388608 + 255) / 256, 256, 0, stream>>>(x, xh, xl, 8388608L);
    k_split<<<(3538944 + 255) / 256, 256, 0, stream>>>(blk_w1, w1h, w1l, 3538944L);
    k_split<<<(3538944 + 255) / 256, 256, 0, stream>>>(blk_w2, w2h, w2l, 3538944L);
    k_split_encw<<<(H_ * 3584 + 255) / 256, 256, 0, stream>>>(enc_w, ench, encl);

    // encoder conv (im2row MFMA GEMM) -> h, then in-place LN
    // grid x=m (m-major): B n-slice stays L2-resident per XCD
    k_mgemm<0><<<dim3(128, 3), 512, 0, stream>>>(xh, xl, ench, encl, enc_b,
                                                 nullptr, h, nullptr, nullptr,
                                                 H_, 3584);
    k_ln<<<BT_, 64, 0, stream>>>(h, h, enc_ln_g, enc_ln_b);

    for (int i = 0; i < 6; ++i) {
        k_dwconv_ln<<<BT_ / 4, 256, 0, stream>>>(h, tmph, tmpl, blk_dw_w + i * H_ * 7,
                                                 blk_dw_b + i * H_, blk_ln_g + i * H_,
                                                 blk_ln_b + i * H_);
        k_mgemm<1><<<dim3(12, 128), 512, 0, stream>>>(
            tmph, tmpl, w1h + (long)i * 589824, w1l + (long)i * 589824,
            blk_b1 + i * H4_, nullptr, nullptr, ht4h, ht4l, H4_, H_);
        k_mgemm<2><<<dim3(3, 128), 512, 0, stream>>>(
            ht4h, ht4l, w2h + (long)i * 589824, w2l + (long)i * 589824,
            blk_b2 + i * H_, h, h, nullptr, nullptr, H_, H4_);
    }

    k_outconv_argmin<<<BT_ / 16, 256, 0, stream>>>(h, out_w, out_b, emb, out);
}

// Round 9
// 1842.541 us; speedup vs baseline: 1.0847x; 1.0039x over previous
//
#include <hip/hip_runtime.h>
#include <math.h>

#define T_   2048
#define DIN  512
#define H_   384
#define H4_  1536
#define BT_  16384

typedef _Float16 half_t;
typedef _Float16 f16x8 __attribute__((ext_vector_type(8)));
typedef float f32x4 __attribute__((ext_vector_type(4)));

#define LO_SCALE 2048.0f
#define LO_INV   4.8828125e-4f

// lgkm-only barrier: prefetched global->VGPR loads stay in flight across it.
__device__ __forceinline__ void lds_barrier() {
    asm volatile("s_waitcnt lgkmcnt(0)\n\ts_barrier" ::: "memory");
}

__device__ __forceinline__ void split2(float v, half_t* hi, half_t* lo) {
    half_t h = (half_t)v;
    *hi = h;
    *lo = (half_t)((v - (float)h) * LO_SCALE);
}

// ---------------------------------------------------------------------------
// fp32 -> (hi, lo*2048) fp16 element-wise split
// ---------------------------------------------------------------------------
__global__ void k_split(const float* __restrict__ in, half_t* __restrict__ hi,
                        half_t* __restrict__ lo, long n) {
    long i = (long)blockIdx.x * 256 + threadIdx.x;
    if (i >= n) return;
    split2(in[i], hi + i, lo + i);
}

// enc_w [H][DIN][7] -> [H][tap*512+i] hi/lo
__global__ void k_split_encw(const float* __restrict__ in, half_t* __restrict__ hi,
                             half_t* __restrict__ lo) {
    int idx = blockIdx.x * 256 + threadIdx.x;
    if (idx >= H_ * 3584) return;
    int n = idx / 3584;
    int r = idx % 3584;
    int tap = r >> 9, i = r & 511;
    split2(in[n * 3584 + i * 7 + tap], hi + idx, lo + idx);
}

// ---------------------------------------------------------------------------
// Row-wise LayerNorm over H=384 (fp32 in/out, in-place safe), one wave per row
// ---------------------------------------------------------------------------
__global__ void k_ln(const float* __restrict__ in, float* __restrict__ out,
                     const float* __restrict__ g, const float* __restrict__ b) {
    int row = blockIdx.x;
    int lane = threadIdx.x;
    const float* ir = in + (long)row * H_;
    float v[6];
    float s = 0.f;
#pragma unroll
    for (int j = 0; j < 6; ++j) { v[j] = ir[lane + (j << 6)]; s += v[j]; }
#pragma unroll
    for (int o = 32; o > 0; o >>= 1) s += __shfl_down(s, o, 64);
    s = __shfl(s, 0, 64);
    float mean = s * (1.f / 384.f);
    float q = 0.f;
#pragma unroll
    for (int j = 0; j < 6; ++j) { float d = v[j] - mean; q += d * d; }
#pragma unroll
    for (int o = 32; o > 0; o >>= 1) q += __shfl_down(q, o, 64);
    q = __shfl(q, 0, 64);
    float rstd = rsqrtf(q * (1.f / 384.f) + 1e-5f);
    float* orow = out + (long)row * H_;
#pragma unroll
    for (int j = 0; j < 6; ++j) {
        int c = lane + (j << 6);
        orow[c] = (v[j] - mean) * rstd * g[c] + b[c];
    }
}

// ---------------------------------------------------------------------------
// Fused depthwise conv (k=7, pad=3) + LayerNorm; emits fp16 hi/lo for GEMM1
// 4 rows per block (one per wave) so the 7-tap t-overlap is L1-resident.
// ---------------------------------------------------------------------------
__global__ __launch_bounds__(256) void k_dwconv_ln(
    const float* __restrict__ h, half_t* __restrict__ oh,
    half_t* __restrict__ ol,
    const float* __restrict__ w, const float* __restrict__ wb,
    const float* __restrict__ g, const float* __restrict__ gb) {
    int row = (blockIdx.x << 2) + (threadIdx.x >> 6);
    int b = row >> 11;
    int t = row & 2047;
    int lane = threadIdx.x & 63;
    const float* hb = h + ((long)b * T_) * H_;
    float v[6];
    float s = 0.f;
#pragma unroll
    for (int j = 0; j < 6; ++j) {
        int c = lane + (j << 6);
        float acc = wb[c];
        const float* wc = w + c * 7;
#pragma unroll
        for (int k = 0; k < 7; ++k) {
            int tt = t + k - 3;
            if ((unsigned)tt < (unsigned)T_)
                acc = fmaf(hb[(long)tt * H_ + c], wc[k], acc);
        }
        v[j] = acc;
        s += acc;
    }
#pragma unroll
    for (int o = 32; o > 0; o >>= 1) s += __shfl_down(s, o, 64);
    s = __shfl(s, 0, 64);
    float mean = s * (1.f / 384.f);
    float q = 0.f;
#pragma unroll
    for (int j = 0; j < 6; ++j) { float d = v[j] - mean; q += d * d; }
#pragma unroll
    for (int o = 32; o > 0; o >>= 1) q += __shfl_down(q, o, 64);
    q = __shfl(q, 0, 64);
    float rstd = rsqrtf(q * (1.f / 384.f) + 1e-5f);
    long ro = (long)row * H_;
#pragma unroll
    for (int j = 0; j < 6; ++j) {
        int c = lane + (j << 6);
        float val = (v[j] - mean) * rstd * g[c] + gb[c];
        split2(val, oh + ro + c, ol + ro + c);
    }
}

// ---------------------------------------------------------------------------
// MFMA fp16x3 GEMM, BM=64 x BN=128, BK=32, 256 threads = 4 waves of 64x32
// wave tile (4x2 frags 16x16x32, wm=0, wn=wid*32). 48 KB LDS -> 3 blocks/CU;
// grid 256m x 3n = 768 blocks = exactly 3 rounds on 256 CUs (no tail).
// XOR-swizzled LDS, double-buffered, one lgkm barrier/iter.
// MODE 0: A = x im2row (K=3584), +bias, fp32 out
// MODE 2: +bias, +res, fp32 out
// LDS halves layout: Ah buf*2048 | Al 4096+buf*2048 | Bh 8192+buf*4096
//                    | Bl 16384+buf*4096   (total 24576 halves = 48 KB)
// ---------------------------------------------------------------------------
template <int MODE>
__global__ __launch_bounds__(256) void k_mgemm64(
    const half_t* __restrict__ Ah, const half_t* __restrict__ Al,
    const half_t* __restrict__ Bh, const half_t* __restrict__ Bl,
    const float* __restrict__ bias, const float* __restrict__ res,
    float* __restrict__ Cf, int N, int K) {
    __shared__ __align__(16) half_t smem[24576];
    const int tid = threadIdx.x;
    const int lane = tid & 63, wid = tid >> 6;
    const int wn = wid << 5;
    const int quad = lane >> 4, l16 = lane & 15;
    const int m0 = blockIdx.x << 6, n0 = blockIdx.y << 7;
    const int ar = tid >> 2;          // staging row 0..63
    const int ak = (tid & 3) << 3;    // k offset (halves), granule = tid&3

    long aoff = 0;
    int tt0 = 0, bq = 0;
    if (MODE == 0) {
        bq = m0 >> 11;
        tt0 = (m0 & 2047) + ar - 3;
    } else {
        aoff = (long)(m0 + ar) * K + ak;
    }
    const long boff0 = (long)(n0 + ar) * K + ak;
    const long boff1 = boff0 + (long)64 * K;

    float4 pAh, pAl, pBh0, pBl0, pBh1, pBl1;
    auto loadregs = [&](int k0) {
        if (MODE == 0) {
            int kk = k0 + ak;
            int tap = kk >> 9, ii = kk & 511;
            int ta = tt0 + tap;
            pAh = pAl = make_float4(0.f, 0.f, 0.f, 0.f);
            if ((unsigned)ta < 2048u) {
                long o = ((long)bq * 2048 + ta) * 512 + ii;
                pAh = *(const float4*)(Ah + o);
                pAl = *(const float4*)(Al + o);
            }
        } else {
            pAh = *(const float4*)(Ah + aoff + k0);
            pAl = *(const float4*)(Al + aoff + k0);
        }
        pBh0 = *(const float4*)(Bh + boff0 + k0);
        pBl0 = *(const float4*)(Bl + boff0 + k0);
        pBh1 = *(const float4*)(Bh + boff1 + k0);
        pBl1 = *(const float4*)(Bl + boff1 + k0);
    };
    // swizzled staging offset (row ar; row+64 keeps the same (row&3) class)
    const int aw = ar * 32 + ((((tid & 3) ^ ar) & 3) << 3);
    auto storebuf = [&](int buf) {
        *(float4*)&smem[buf * 2048 + aw] = pAh;
        *(float4*)&smem[4096 + buf * 2048 + aw] = pAl;
        int b = 8192 + buf * 4096 + aw;
        *(float4*)&smem[b] = pBh0;
        *(float4*)&smem[b + 2048] = pBh1;
        *(float4*)&smem[b + 8192] = pBl0;
        *(float4*)&smem[b + 8192 + 2048] = pBl1;
    };

    f32x4 acc1[4][2] = {};
    f32x4 acc2[4][2] = {};

    loadregs(0);
    storebuf(0);
    const int nIter = K >> 5;
    int cur = 0;
    const int sw = ((quad ^ l16) & 3) << 3;   // read-side swizzle
    for (int it = 0; it < nIter; ++it) {
        if (it + 1 < nIter) loadregs((it + 1) << 5);
        lds_barrier();
        const int ab = cur * 2048 + l16 * 32 + sw;
        const int bb = 8192 + cur * 4096 + (wn + l16) * 32 + sw;
        f16x8 fah[4], fal[4], fgh[2], fgl[2];
#pragma unroll
        for (int f = 0; f < 4; ++f) {
            fah[f] = *(const f16x8*)&smem[ab + f * 512];
            fal[f] = *(const f16x8*)&smem[ab + 4096 + f * 512];
        }
#pragma unroll
        for (int g = 0; g < 2; ++g) {
            fgh[g] = *(const f16x8*)&smem[bb + g * 512];
            fgl[g] = *(const f16x8*)&smem[bb + 8192 + g * 512];
        }
#pragma unroll
        for (int f = 0; f < 4; ++f)
#pragma unroll
            for (int g = 0; g < 2; ++g)
                acc2[f][g] = __builtin_amdgcn_mfma_f32_16x16x32_f16(fah[f], fgl[g], acc2[f][g], 0, 0, 0);
#pragma unroll
        for (int f = 0; f < 4; ++f)
#pragma unroll
            for (int g = 0; g < 2; ++g)
                acc2[f][g] = __builtin_amdgcn_mfma_f32_16x16x32_f16(fal[f], fgh[g], acc2[f][g], 0, 0, 0);
#pragma unroll
        for (int f = 0; f < 4; ++f)
#pragma unroll
            for (int g = 0; g < 2; ++g)
                acc1[f][g] = __builtin_amdgcn_mfma_f32_16x16x32_f16(fah[f], fgh[g], acc1[f][g], 0, 0, 0);
        if (it + 1 < nIter) storebuf(cur ^ 1);
        cur ^= 1;
    }

    float bv[2];
    bv[0] = bias[n0 + wn + l16];
    bv[1] = bias[n0 + wn + 16 + l16];

#pragma unroll
    for (int f = 0; f < 4; ++f)
#pragma unroll
        for (int g = 0; g < 2; ++g)
#pragma unroll
            for (int r = 0; r < 4; ++r) {
                long row = m0 + f * 16 + quad * 4 + r;
                int col = n0 + wn + g * 16 + l16;
                float v = acc1[f][g][r] + acc2[f][g][r] * LO_INV + bv[g];
                long o = row * N + col;
                if (MODE == 2) v += res[o];
                Cf[o] = v;
            }
}

// ---------------------------------------------------------------------------
// MFMA fp16x3 GEMM (G1): BM=128, BN=128, BK=32; 512 threads = 8 waves of
// 64x32 wave tile. +bias, exact GELU, fp16 hi/lo out. Grid 12n x 128m = 1536
// blocks = exactly 3 rounds at 2 blocks/CU (64 KB LDS).
// ---------------------------------------------------------------------------
#define APLANE 4096
#define ASL_OFF 8192
#define BSH_OFF 16384
#define BSL_OFF 24576

__global__ __launch_bounds__(512) void k_mgemm1(
    const half_t* __restrict__ Ah, const half_t* __restrict__ Al,
    const half_t* __restrict__ Bh, const half_t* __restrict__ Bl,
    const float* __restrict__ bias,
    half_t* __restrict__ Ch, half_t* __restrict__ Cl, int N, int K) {
    __shared__ __align__(16) half_t smem[32768];
    const int tid = threadIdx.x;
    const int lane = tid & 63, wid = tid >> 6;
    const int wm = (wid >> 2) << 6, wn = (wid & 3) << 5;
    const int quad = lane >> 4, l16 = lane & 15;
    const int m0 = blockIdx.y << 7, n0 = blockIdx.x << 7;
    const int ar = tid >> 2;
    const int ak = (tid & 3) << 3;

    const long aoff = (long)(m0 + ar) * K + ak;
    const long boff = (long)(n0 + ar) * K + ak;

    float4 pAh, pAl, pBh, pBl;
    auto loadregs = [&](int k0) {
        pAh = *(const float4*)(Ah + aoff + k0);
        pAl = *(const float4*)(Al + aoff + k0);
        pBh = *(const float4*)(Bh + boff + k0);
        pBl = *(const float4*)(Bl + boff + k0);
    };
    const int aw = ar * 32 + ((((tid & 3) ^ ar) & 3) << 3);
    auto storebuf = [&](int buf) {
        int a = buf * APLANE + aw;
        *(float4*)&smem[a] = pAh;
        *(float4*)&smem[a + ASL_OFF] = pAl;
        *(float4*)&smem[a + BSH_OFF] = pBh;
        *(float4*)&smem[a + BSL_OFF] = pBl;
    };

    f32x4 acc1[4][2] = {};
    f32x4 acc2[4][2] = {};

    loadregs(0);
    storebuf(0);
    const int nIter = K >> 5;
    int cur = 0;
    const int sw = ((quad ^ l16) & 3) << 3;
    for (int it = 0; it < nIter; ++it) {
        if (it + 1 < nIter) loadregs((it + 1) << 5);
        lds_barrier();
        const int ab = cur * APLANE + (wm + l16) * 32 + sw;
        const int bb = BSH_OFF + cur * APLANE + (wn + l16) * 32 + sw;
        f16x8 fah[4], fal[4], fgh[2], fgl[2];
#pragma unroll
        for (int f = 0; f < 4; ++f) {
            fah[f] = *(const f16x8*)&smem[ab + f * 512];
            fal[f] = *(const f16x8*)&smem[ab + ASL_OFF + f * 512];
        }
#pragma unroll
        for (int g = 0; g < 2; ++g) {
            fgh[g] = *(const f16x8*)&smem[bb + g * 512];
            fgl[g] = *(const f16x8*)&smem[bb + ASL_OFF + g * 512];
        }
#pragma unroll
        for (int f = 0; f < 4; ++f)
#pragma unroll
            for (int g = 0; g < 2; ++g)
                acc2[f][g] = __builtin_amdgcn_mfma_f32_16x16x32_f16(fah[f], fgl[g], acc2[f][g], 0, 0, 0);
#pragma unroll
        for (int f = 0; f < 4; ++f)
#pragma unroll
            for (int g = 0; g < 2; ++g)
                acc2[f][g] = __builtin_amdgcn_mfma_f32_16x16x32_f16(fal[f], fgh[g], acc2[f][g], 0, 0, 0);
#pragma unroll
        for (int f = 0; f < 4; ++f)
#pragma unroll
            for (int g = 0; g < 2; ++g)
                acc1[f][g] = __builtin_amdgcn_mfma_f32_16x16x32_f16(fah[f], fgh[g], acc1[f][g], 0, 0, 0);
        if (it + 1 < nIter) storebuf(cur ^ 1);
        cur ^= 1;
    }

    float bv[2];
    bv[0] = bias[n0 + wn + l16];
    bv[1] = bias[n0 + wn + 16 + l16];

    // two passes over 64-col halves; staging planes stride 72: hi @0, lo @9216
#pragma unroll
    for (int h2 = 0; h2 < 2; ++h2) {
        __syncthreads();
        if (((wid >> 1) & 1) == h2) {
            int cbase = (wid & 1) << 5;
#pragma unroll
            for (int f = 0; f < 4; ++f)
#pragma unroll
                for (int g = 0; g < 2; ++g)
#pragma unroll
                    for (int r = 0; r < 4; ++r) {
                        int rm = wm + f * 16 + quad * 4 + r;
                        int cn = cbase + g * 16 + l16;
                        float v = acc1[f][g][r] + acc2[f][g][r] * LO_INV + bv[g];
                        v = 0.5f * v * (1.0f + erff(v * 0.70710678118654752f));
                        half_t hh = (half_t)v;
                        smem[rm * 72 + cn] = hh;
                        smem[9216 + rm * 72 + cn] = (half_t)((v - (float)hh) * LO_SCALE);
                    }
        }
        __syncthreads();
        int row = tid >> 2, c16 = (tid & 3) << 4;
        long go = (long)(m0 + row) * N + n0 + (h2 << 6) + c16;
        *(float4*)(Ch + go)     = *(const float4*)&smem[row * 72 + c16];
        *(float4*)(Ch + go + 8) = *(const float4*)&smem[row * 72 + c16 + 8];
        *(float4*)(Cl + go)     = *(const float4*)&smem[9216 + row * 72 + c16];
        *(float4*)(Cl + go + 8) = *(const float4*)&smem[9216 + row * 72 + c16 + 8];
    }
}

// ---------------------------------------------------------------------------
// Fused out-conv (pointwise, C=8) + nearest-embedding argmin over K=8192
// ---------------------------------------------------------------------------
__global__ __launch_bounds__(256) void k_outconv_argmin(
    const float* __restrict__ h, const float* __restrict__ ow,
    const float* __restrict__ ob, const float* __restrict__ emb,
    int* __restrict__ outIdx) {
    __shared__ float hs[16][H_ + 1];
    __shared__ float zs[16][8];
    __shared__ float es[16 * 516];
    __shared__ float rb[16][16];
    __shared__ int ri[16][16];
    const int tid = threadIdx.x;
    const int row0 = blockIdx.x << 4;

    for (int i = tid; i < 16 * (H_ / 4); i += 256) {
        int r = i / 96;
        int c4 = (i % 96) << 2;
        float4 v = *(const float4*)&h[((long)(row0 + r)) * H_ + c4];
        hs[r][c4] = v.x; hs[r][c4 + 1] = v.y; hs[r][c4 + 2] = v.z; hs[r][c4 + 3] = v.w;
    }
    __syncthreads();

    if (tid < 128) {
        int r = tid & 15, c = tid >> 4;
        float acc = ob[c];
        const float* wc = ow + c * H_;
        for (int j = 0; j < H_; ++j) acc = fmaf(hs[r][j], wc[j], acc);
        zs[r][c] = acc;
    }
    __syncthreads();

    const int r = tid & 15;
    const int sl = tid >> 4;
    float z0 = zs[r][0], z1 = zs[r][1], z2 = zs[r][2], z3 = zs[r][3];
    float z4 = zs[r][4], z5 = zs[r][5], z6 = zs[r][6], z7 = zs[r][7];
    float best = 3.4e38f;
    int bi = 0;

    for (int ch = 0; ch < 8; ++ch) {
        __syncthreads();
        for (int i = tid; i < 2048; i += 256) {
            int e = i >> 1;
            int half = (i & 1) << 2;
            float4 src = *(const float4*)&emb[(((long)(ch << 10)) + e) * 8 + half];
            *(float4*)&es[(e >> 6) * 516 + ((e & 63) << 3) + half] = src;
        }
        __syncthreads();
        const float* ep = es + sl * 516;
        int gbase = (ch << 10) + (sl << 6);
#pragma unroll 4
        for (int j = 0; j < 64; ++j) {
            float4 e0 = *(const float4*)(ep + (j << 3));
            float4 e1 = *(const float4*)(ep + (j << 3) + 4);
            float t, d;
            t = e0.x - z0; d = t * t;
            t = e0.y - z1; d = fmaf(t, t, d);
            t = e0.z - z2; d = fmaf(t, t, d);
            t = e0.w - z3; d = fmaf(t, t, d);
            t = e1.x - z4; d = fmaf(t, t, d);
            t = e1.y - z5; d = fmaf(t, t, d);
            t = e1.z - z6; d = fmaf(t, t, d);
            t = e1.w - z7; d = fmaf(t, t, d);
            if (d < best) { best = d; bi = gbase + j; }
        }
    }
    rb[r][sl] = best;
    ri[r][sl] = bi;
    __syncthreads();
    if (sl == 0) {
        float bb = rb[r][0];
        int bbi = ri[r][0];
#pragma unroll
        for (int s2 = 1; s2 < 16; ++s2) {
            float v = rb[r][s2];
            int i2 = ri[r][s2];
            if (v < bb || (v == bb && i2 < bbi)) { bb = v; bbi = i2; }
        }
        outIdx[row0 + r] = bbi;
    }
}

// ---------------------------------------------------------------------------
// host launcher
// ---------------------------------------------------------------------------
extern "C" void kernel_launch(void* const* d_in, const int* in_sizes, int n_in,
                              void* d_out, int out_size, void* d_ws, size_t ws_size,
                              hipStream_t stream) {
    const float* x        = (const float*)d_in[0];
    const float* enc_w    = (const float*)d_in[1];
    const float* enc_b    = (const float*)d_in[2];
    const float* enc_ln_g = (const float*)d_in[3];
    const float* enc_ln_b = (const float*)d_in[4];
    const float* blk_dw_w = (const float*)d_in[5];
    const float* blk_dw_b = (const float*)d_in[6];
    const float* blk_ln_g = (const float*)d_in[7];
    const float* blk_ln_b = (const float*)d_in[8];
    const float* blk_w1   = (const float*)d_in[9];
    const float* blk_b1   = (const float*)d_in[10];
    const float* blk_w2   = (const float*)d_in[11];
    const float* blk_b2   = (const float*)d_in[12];
    const float* out_w    = (const float*)d_in[13];
    const float* out_b    = (const float*)d_in[14];
    const float* emb      = (const float*)d_in[15];
    int* out = (int*)d_out;

    char* base = (char*)d_ws;
    float*  h    = (float*)base;                       // 25165824 B
    half_t* tmph = (half_t*)(base + 25165824);         // 12582912 B
    half_t* tmpl = (half_t*)(base + 37748736);         // 12582912 B
    half_t* ht4h = (half_t*)(base + 50331648);         // 50331648 B
    half_t* ht4l = (half_t*)(base + 100663296);        // 50331648 B
    half_t* ench = (half_t*)(base + 150994944);        // 2752512 B
    half_t* encl = (half_t*)(base + 153747456);        // 2752512 B
    half_t* w1h  = (half_t*)(base + 156499968);        // 7077888 B
    half_t* w1l  = (half_t*)(base + 163577856);        // 7077888 B
    half_t* w2h  = (half_t*)(base + 170655744);        // 7077888 B
    half_t* w2l  = (half_t*)(base + 177733632);        // 7077888 B
    // x hi/lo alias the ht4 region (dead until first GEMM1)
    half_t* xh = ht4h;                                  // 16777216 B
    half_t* xl = (half_t*)(base + 50331648 + 16777216); // 16777216 B

    k_split<<<(8388608 + 255) / 256, 256, 0, stream>>>(x, xh, xl, 8388608L);
    k_split<<<(3538944 + 255) / 256, 256, 0, stream>>>(blk_w1, w1h, w1l, 3538944L);
    k_split<<<(3538944 + 255) / 256, 256, 0, stream>>>(blk_w2, w2h, w2l, 3538944L);
    k_split_encw<<<(H_ * 3584 + 255) / 256, 256, 0, stream>>>(enc_w, ench, encl);

    // encoder conv (im2row MFMA GEMM) -> h, then in-place LN
    // 768 blocks = exact 3 rounds at 3 blocks/CU; m-fastest so the B n-slice
    // stays L2-resident per round
    k_mgemm64<0><<<dim3(256, 3), 256, 0, stream>>>(xh, xl, ench, encl, enc_b,
                                                   nullptr, h, H_, 3584);
    k_ln<<<BT_, 64, 0, stream>>>(h, h, enc_ln_g, enc_ln_b);

    for (int i = 0; i < 6; ++i) {
        k_dwconv_ln<<<BT_ / 4, 256, 0, stream>>>(h, tmph, tmpl, blk_dw_w + i * H_ * 7,
                                                 blk_dw_b + i * H_, blk_ln_g + i * H_,
                                                 blk_ln_b + i * H_);
        k_mgemm1<<<dim3(12, 128), 512, 0, stream>>>(
            tmph, tmpl, w1h + (long)i * 589824, w1l + (long)i * 589824,
            blk_b1 + i * H4_, ht4h, ht4l, H4_, H_);
        k_mgemm64<2><<<dim3(256, 3), 256, 0, stream>>>(
            ht4h, ht4l, w2h + (long)i * 589824, w2l + (long)i * 589824,
            blk_b2 + i * H_, h, h, H_, H4_);
    }

    k_outconv_argmin<<<BT_ / 16, 256, 0, stream>>>(h, out_w, out_b, emb, out);
}